// Round 14
// baseline (100.053 us; speedup 1.0000x reference)
//
#include <hip/hip_runtime.h>
#include <hip/hip_fp16.h>

// ProsGraphNet on MI355X — R14: R13 + 32-deep gather windows (single 16-row
// batch, sched_barrier-forced, launch_bounds(256,3)) + fused head kernel.
//  - every node has exactly DEG=16 in-edges -> deg == 17, coef == 1/17
//  - edges sorted by dst: node i's incoming srcs are src[16i..16i+15]
//  - graph g -> XCD g (blockIdx&7): gathers hit the 4MB per-XCD L2
//  - t1 fp8 e4m3 32B rows, t2 fp16 32B rows (R11 verified hybrid)
//  - fp32 atomic corr accumulation, zeroed in k_pack (R13 verified)

#define NN 131072
#define SS 16384
#define NB 8
#define DEG 16
#define INV17 (1.0f / 17.0f)

typedef float floatx2 __attribute__((ext_vector_type(2)));

__device__ __forceinline__ unsigned pkh2(float a, float b) {
    union { __half2 h2; unsigned u; } c;
    c.h2 = __floats2half2_rn(a, b);
    return c.u;
}

__device__ __forceinline__ unsigned pk4fp8(float a, float b, float c, float d) {
    unsigned lo = __builtin_amdgcn_cvt_pk_fp8_f32(a, b, 0, false);
    return __builtin_amdgcn_cvt_pk_fp8_f32(c, d, lo, true);
}

// accumulate 4 fp8 values packed in uint32 u into acc[base..base+4)
#define ACCU32(acc, base, u) { \
    floatx2 lo_ = __builtin_amdgcn_cvt_pk_f32_fp8((u), false); \
    floatx2 hi_ = __builtin_amdgcn_cvt_pk_f32_fp8((u), true); \
    acc[(base) + 0] += lo_[0]; acc[(base) + 1] += lo_[1]; \
    acc[(base) + 2] += hi_[0]; acc[(base) + 3] += hi_[1]; }

// accumulate a 32B fp16 row (2 uint4 = 8 half2) into a[8]
#define HACC8(a, r0, r1) { \
    const __half2* p_ = reinterpret_cast<const __half2*>(&(r0)); \
    a[0] = __hadd2(a[0], p_[0]); a[1] = __hadd2(a[1], p_[1]); \
    a[2] = __hadd2(a[2], p_[2]); a[3] = __hadd2(a[3], p_[3]); \
    p_ = reinterpret_cast<const __half2*>(&(r1)); \
    a[4] = __hadd2(a[4], p_[0]); a[5] = __hadd2(a[5], p_[1]); \
    a[6] = __hadd2(a[6], p_[2]); a[7] = __hadd2(a[7], p_[3]); }

// ---- pack x (N,3) fp32 -> float4 rows, XCD-affine; blocks 0..7 zero corr -
__global__ __launch_bounds__(256) void k_pack(
    const float* __restrict__ xA, const float* __restrict__ xB,
    float4* __restrict__ x4A, float4* __restrict__ x4B,
    float* __restrict__ corr) {
    int b = blockIdx.x;
    if (b < 8) corr[b * 256 + threadIdx.x] = 0.0f;    // zero accumulators
    int g = b & 7, side = (b >> 3) & 1, chunk = b >> 4;   // 1024 blocks
    const float* x = side ? xB : xA;
    float4* x4 = side ? x4B : x4A;
    int i = g * SS + chunk * 256 + threadIdx.x;
    x4[i] = make_float4(x[3 * i], x[3 * i + 1], x[3 * i + 2], 0.0f);
}

// ---- layer1: agg(x4) -> @W1+b1 -> relu -> @W2 -> t1 fp8 32B rows --------
__global__ __launch_bounds__(256, 4) void k_gcn1(
    const int* __restrict__ srcA, const int* __restrict__ srcB,
    const float4* __restrict__ x4A, const float4* __restrict__ x4B,
    const float* __restrict__ W1, const float* __restrict__ b1,
    const float* __restrict__ W2,
    unsigned* __restrict__ t1A, unsigned* __restrict__ t1B) {
    int b = blockIdx.x;
    int g = b & 7, side = (b >> 3) & 1, chunk = b >> 4;   // 1024 blocks
    const int* src = side ? srcB : srcA;
    const float4* x4 = side ? x4B : x4A;
    unsigned* t1 = side ? t1B : t1A;
    int i = g * SS + chunk * 256 + threadIdx.x;

    const int4* sp = reinterpret_cast<const int4*>(src + (size_t)i * DEG);
    int4 s0 = sp[0], s1 = sp[1], s2 = sp[2], s3 = sp[3];
    int nb[16] = {s0.x, s0.y, s0.z, s0.w, s1.x, s1.y, s1.z, s1.w,
                  s2.x, s2.y, s2.z, s2.w, s3.x, s3.y, s3.z, s3.w};

    float4 self = x4[i];
    float4 v[16];
#pragma unroll
    for (int k = 0; k < 16; ++k) v[k] = x4[nb[k]];
    __builtin_amdgcn_sched_barrier(0);     // all 16 gathers issued first
    float ax0 = self.x, ay0 = self.y, az0 = self.z;
    float ax1 = 0.f, ay1 = 0.f, az1 = 0.f;
#pragma unroll
    for (int k = 0; k < 16; k += 2) {
        ax0 += v[k].x; ay0 += v[k].y; az0 += v[k].z;
        ax1 += v[k + 1].x; ay1 += v[k + 1].y; az1 += v[k + 1].z;
    }
    float ax = (ax0 + ax1) * INV17, ay = (ay0 + ay1) * INV17, az = (az0 + az1) * INV17;

    float h[32];
#pragma unroll
    for (int k = 0; k < 32; ++k) {
        float hv = fmaf(ax, W1[k], fmaf(ay, W1[32 + k], fmaf(az, W1[64 + k], b1[k])));
        h[k] = fmaxf(hv, 0.0f);
    }
    float t[24];
#pragma unroll
    for (int j = 0; j < 24; ++j) t[j] = 0.0f;
#pragma unroll
    for (int k = 0; k < 32; ++k) {
        float hv = h[k];
#pragma unroll
        for (int j = 0; j < 24; ++j) t[j] = fmaf(hv, W2[k * 24 + j], t[j]);
    }
    uint4* row = reinterpret_cast<uint4*>(t1 + (size_t)i * 8);   // 32B rows
    row[0] = make_uint4(pk4fp8(t[0], t[1], t[2], t[3]),
                        pk4fp8(t[4], t[5], t[6], t[7]),
                        pk4fp8(t[8], t[9], t[10], t[11]),
                        pk4fp8(t[12], t[13], t[14], t[15]));
    row[1] = make_uint4(pk4fp8(t[16], t[17], t[18], t[19]),
                        pk4fp8(t[20], t[21], t[22], t[23]), 0u, 0u);
}

// ---- layer2: agg(t1 fp8)+b2 -> relu -> @W3 -> t2 fp16 32B rows ----------
// single 16-row batch: 32 uint4 in flight (sched_barrier-forced).
__global__ __launch_bounds__(256, 3) void k_gcn2(
    const int* __restrict__ srcA, const int* __restrict__ srcB,
    const unsigned* __restrict__ t1A, const unsigned* __restrict__ t1B,
    const float* __restrict__ b2, const float* __restrict__ W3,
    __half* __restrict__ t2A, __half* __restrict__ t2B) {
    int b = blockIdx.x;
    int g = b & 7, side = (b >> 3) & 1, chunk = b >> 4;   // 1024 blocks
    const int* src = side ? srcB : srcA;
    const uint4* t1v = reinterpret_cast<const uint4*>(side ? t1B : t1A); // row = 2 uint4
    __half* t2 = side ? t2B : t2A;
    int i = g * SS + chunk * 256 + threadIdx.x;

    const int4* sp = reinterpret_cast<const int4*>(src + (size_t)i * DEG);
    int4 s0 = sp[0], s1 = sp[1], s2 = sp[2], s3 = sp[3];
    int nb[16] = {s0.x, s0.y, s0.z, s0.w, s1.x, s1.y, s1.z, s1.w,
                  s2.x, s2.y, s2.z, s2.w, s3.x, s3.y, s3.z, s3.w};

    float acc[24];
#pragma unroll
    for (int j = 0; j < 24; ++j) acc[j] = 0.0f;
    {   // self row (coalesced)
        uint4 r0 = t1v[(size_t)i * 2], r1 = t1v[(size_t)i * 2 + 1];
        ACCU32(acc, 0, r0.x); ACCU32(acc, 4, r0.y);
        ACCU32(acc, 8, r0.z); ACCU32(acc, 12, r0.w);
        ACCU32(acc, 16, r1.x); ACCU32(acc, 20, r1.y);
    }
    {
        uint4 ra[16], rb[16];
#pragma unroll
        for (int k = 0; k < 16; ++k) {
            int base = nb[k] * 2;
            ra[k] = t1v[base]; rb[k] = t1v[base + 1];
        }
        __builtin_amdgcn_sched_barrier(0);     // 32 loads issued before any cvt
#pragma unroll
        for (int k = 0; k < 16; ++k) {
            ACCU32(acc, 0, ra[k].x); ACCU32(acc, 4, ra[k].y);
            ACCU32(acc, 8, ra[k].z); ACCU32(acc, 12, ra[k].w);
            ACCU32(acc, 16, rb[k].x); ACCU32(acc, 20, rb[k].y);
        }
    }
    float z[24];
#pragma unroll
    for (int j = 0; j < 24; ++j)
        z[j] = fmaxf(fmaf(acc[j], INV17, b2[j]), 0.0f);

    float o[16];
#pragma unroll
    for (int j = 0; j < 16; ++j) o[j] = 0.0f;
#pragma unroll
    for (int k = 0; k < 24; ++k) {
        const float4* wr = reinterpret_cast<const float4*>(W3 + k * 16);
        float4 w0 = wr[0], w1 = wr[1], w2 = wr[2], w3 = wr[3];
        float zk = z[k];
        o[0] = fmaf(zk, w0.x, o[0]);  o[1] = fmaf(zk, w0.y, o[1]);
        o[2] = fmaf(zk, w0.z, o[2]);  o[3] = fmaf(zk, w0.w, o[3]);
        o[4] = fmaf(zk, w1.x, o[4]);  o[5] = fmaf(zk, w1.y, o[5]);
        o[6] = fmaf(zk, w1.z, o[6]);  o[7] = fmaf(zk, w1.w, o[7]);
        o[8] = fmaf(zk, w2.x, o[8]);  o[9] = fmaf(zk, w2.y, o[9]);
        o[10] = fmaf(zk, w2.z, o[10]); o[11] = fmaf(zk, w2.w, o[11]);
        o[12] = fmaf(zk, w3.x, o[12]); o[13] = fmaf(zk, w3.y, o[13]);
        o[14] = fmaf(zk, w3.z, o[14]); o[15] = fmaf(zk, w3.w, o[15]);
    }
    uint4* out = reinterpret_cast<uint4*>((char*)t2 + (size_t)i * 32);
    out[0] = make_uint4(pkh2(o[0], o[1]), pkh2(o[2], o[3]), pkh2(o[4], o[5]), pkh2(o[6], o[7]));
    out[1] = make_uint4(pkh2(o[8], o[9]), pkh2(o[10], o[11]), pkh2(o[12], o[13]), pkh2(o[14], o[15]));
}

// ---- layer3 + corr: agg(t2 fp16)+b3 -> l2norm -> LDS -> atomic corr -----
// single 16-row batch: 32 uint4 in flight (sched_barrier-forced).
__global__ __launch_bounds__(256, 3) void k_gcn3corr(
    const int* __restrict__ srcA, const int* __restrict__ srcB,
    const __half* __restrict__ t2A, const __half* __restrict__ t2B,
    const float* __restrict__ b3, float* __restrict__ corr) {
    __shared__ float sF[2 * 128 * 20];    // stride 20 floats: bank-safe
    int b = blockIdx.x;
    int g = b & 7, chunk = b >> 3;        // chunk 0..127
    int t = threadIdx.x;
    int s = t >> 7, n = t & 127;
    const int* src = s ? srcB : srcA;
    const uint4* t2v = reinterpret_cast<const uint4*>(s ? t2B : t2A);  // row = 2 uint4
    int i = g * SS + chunk * 128 + n;

    const int4* sp = reinterpret_cast<const int4*>(src + (size_t)i * DEG);
    int4 s0 = sp[0], s1 = sp[1], s2 = sp[2], s3 = sp[3];
    int nb[16] = {s0.x, s0.y, s0.z, s0.w, s1.x, s1.y, s1.z, s1.w,
                  s2.x, s2.y, s2.z, s2.w, s3.x, s3.y, s3.z, s3.w};

    __half2 accA[8], accB[8];
    {
        uint4 r0 = t2v[(size_t)i * 2], r1 = t2v[(size_t)i * 2 + 1];
        const __half2* p = reinterpret_cast<const __half2*>(&r0);
        accA[0] = p[0]; accA[1] = p[1]; accA[2] = p[2]; accA[3] = p[3];
        p = reinterpret_cast<const __half2*>(&r1);
        accA[4] = p[0]; accA[5] = p[1]; accA[6] = p[2]; accA[7] = p[3];
        __half2 z2v = __floats2half2_rn(0.0f, 0.0f);
#pragma unroll
        for (int j = 0; j < 8; ++j) accB[j] = z2v;
    }
    {
        uint4 ra[16], rb[16];
#pragma unroll
        for (int k = 0; k < 16; ++k) {
            int base = nb[k] * 2;
            ra[k] = t2v[base]; rb[k] = t2v[base + 1];
        }
        __builtin_amdgcn_sched_barrier(0);     // 32 loads issued before any add
#pragma unroll
        for (int k = 0; k < 16; k += 2) {
            HACC8(accA, ra[k], rb[k]);
            HACC8(accB, ra[k + 1], rb[k + 1]);
        }
    }
    float acc[16];
#pragma unroll
    for (int j = 0; j < 8; ++j) {
        __half2 sum = __hadd2(accA[j], accB[j]);
        acc[2 * j] = __low2float(sum);
        acc[2 * j + 1] = __high2float(sum);
    }
    float ss = 0.0f;
#pragma unroll
    for (int j = 0; j < 16; ++j) {
        acc[j] = fmaf(acc[j], INV17, b3[j]);
        ss = fmaf(acc[j], acc[j], ss);
    }
    float sc = rsqrtf(ss + 1e-6f);
    float* dst = &sF[(s * 128 + n) * 20];
#pragma unroll
    for (int c = 0; c < 4; ++c)
        reinterpret_cast<float4*>(dst)[c] =
            make_float4(acc[4 * c] * sc, acc[4 * c + 1] * sc,
                        acc[4 * c + 2] * sc, acc[4 * c + 3] * sc);
    __syncthreads();

    int c = t >> 4, d = t & 15;
    const float* sA = sF;
    const float* sB = sF + 128 * 20;
    float pacc = 0.0f;
#pragma unroll 8
    for (int m = 0; m < 128; ++m)
        pacc = fmaf(sA[m * 20 + c], sB[m * 20 + d], pacc);
    atomicAdd(&corr[g * 256 + t], pacc);   // XCD-local L2 atomic, 128/addr
}

// ---- fused head: corr -> relu/l2norm/conv1 per graph -> BN1 -> conv2 ----
// one block, 512 threads; two graphs processed per 256-thread half.
__global__ __launch_bounds__(512) void k_head(
    const float* __restrict__ corr,
    const float* __restrict__ c1w, const float* __restrict__ c1b,
    const float* __restrict__ g1, const float* __restrict__ be1,
    const float* __restrict__ c2w, const float* __restrict__ c2b,
    const float* __restrict__ g2, const float* __restrict__ be2,
    const float* __restrict__ lw, const float* __restrict__ lb,
    float* __restrict__ out) {
    __shared__ float cn[2][256];
    __shared__ float scale[2][16];
    __shared__ float ph[2][256];
    __shared__ float y1s[8][128];
    __shared__ float z1[1024];
    __shared__ float w2t[8192];
    __shared__ float y2[512];
    __shared__ float z2[512];
    int t = threadIdx.x;
    int hg = t >> 8, tt = t & 255;        // half 0/1, local thread

    // ---- stage 1 (head1) for 8 graphs, 2 at a time ----
    for (int gg = 0; gg < 4; ++gg) {
        int g = gg * 2 + hg;
        cn[hg][tt] = fmaxf(corr[g * 256 + tt], 0.0f);
        __syncthreads();
        if (tt < 16) {
            float q = 0.0f;
            for (int c = 0; c < 16; ++c) { float v = cn[hg][c * 16 + tt]; q = fmaf(v, v, q); }
            scale[hg][tt] = rsqrtf(q + 1e-6f);
        }
        __syncthreads();
        float v = cn[hg][tt] * scale[hg][tt & 15];
        __syncthreads();
        cn[hg][tt] = v;
        __syncthreads();
        int o = tt >> 1, half = tt & 1;
        const float4* w = reinterpret_cast<const float4*>(c1w + o * 256 + half * 128);
        const float4* cc = reinterpret_cast<const float4*>(&cn[hg][half * 128]);
        float a = 0.0f;
#pragma unroll
        for (int q = 0; q < 32; ++q) {
            float4 wv = w[q]; float4 cv = cc[q];
            a = fmaf(wv.x, cv.x, a); a = fmaf(wv.y, cv.y, a);
            a = fmaf(wv.z, cv.z, a); a = fmaf(wv.w, cv.w, a);
        }
        ph[hg][tt] = a;
        __syncthreads();
        if (tt < 128) y1s[g][tt] = ph[hg][2 * tt] + ph[hg][2 * tt + 1] + c1b[tt];
        __syncthreads();
    }

    // ---- stage 2 (head2) ----
    if (t < 128) {
        float m = 0.0f;
        for (int b = 0; b < 8; ++b) m += y1s[b][t];
        m *= 0.125f;
        float v = 0.0f;
        for (int b = 0; b < 8; ++b) { float d = y1s[b][t] - m; v = fmaf(d, d, v); }
        v *= 0.125f;
        float sc = rsqrtf(v + 1e-5f) * g1[t], sh = be1[t];
        for (int b = 0; b < 8; ++b)
            z1[b * 128 + t] = fmaxf(fmaf(y1s[b][t] - m, sc, sh), 0.0f);
    }
    int o2 = t & 63, cb = (t >> 6) * 16;
    for (int k = 0; k < 16; ++k) {
        int c = cb + k;
        w2t[c * 64 + o2] = c2w[(o2 * 128 + c) * 9 + 4];   // center tap
    }
    __syncthreads();
    {
        int b = t >> 6;
        float a = 0.0f;
        for (int c = 0; c < 128; ++c) a = fmaf(z1[b * 128 + c], w2t[c * 64 + o2], a);
        y2[t] = a + c2b[o2];
    }
    __syncthreads();
    if (t < 64) {
        float m = 0.0f;
        for (int b = 0; b < 8; ++b) m += y2[b * 64 + t];
        m *= 0.125f;
        float v = 0.0f;
        for (int b = 0; b < 8; ++b) { float d = y2[b * 64 + t] - m; v = fmaf(d, d, v); }
        v *= 0.125f;
        float sc = rsqrtf(v + 1e-5f) * g2[t], sh = be2[t];
        for (int b = 0; b < 8; ++b)
            z2[b * 64 + t] = fmaxf(fmaf(y2[b * 64 + t] - m, sc, sh), 0.0f);
    }
    __syncthreads();
    if (t < 48) {
        int b = t / 6, k = t - b * 6;
        float a = 0.0f;
        for (int c = 0; c < 64; ++c) a = fmaf(z2[b * 64 + c], lw[k * 64 + c], a);
        float th = 0.1f * (a + lb[k]);
        const float ident[6] = {1.0f, 0.0f, 0.0f, 0.0f, 1.0f, 0.0f};
        out[t] = th + ident[k];
    }
}

extern "C" void kernel_launch(void* const* d_in, const int* in_sizes, int n_in,
                              void* d_out, int out_size, void* d_ws, size_t ws_size,
                              hipStream_t stream) {
    const float* xA = (const float*)d_in[0];
    const float* xB = (const float*)d_in[1];
    const int* srcA = (const int*)d_in[2];
    const int* srcB = (const int*)d_in[3];
    const float* W1 = (const float*)d_in[4];
    const float* b1 = (const float*)d_in[5];
    const float* W2 = (const float*)d_in[6];
    const float* b2 = (const float*)d_in[7];
    const float* W3 = (const float*)d_in[8];
    const float* b3 = (const float*)d_in[9];
    const float* c1w = (const float*)d_in[10];
    const float* c1b = (const float*)d_in[11];
    const float* g1 = (const float*)d_in[12];
    const float* be1 = (const float*)d_in[13];
    const float* c2w = (const float*)d_in[14];
    const float* c2b = (const float*)d_in[15];
    const float* g2 = (const float*)d_in[16];
    const float* be2 = (const float*)d_in[17];
    const float* lw = (const float*)d_in[18];
    const float* lb = (const float*)d_in[19];

    char* base = (char*)d_ws;
    size_t off = 0;
    float4* x4A = (float4*)(base + off); off += (size_t)NN * 16;
    float4* x4B = (float4*)(base + off); off += (size_t)NN * 16;
    unsigned* t1A = (unsigned*)(base + off); off += (size_t)NN * 32;  // fp8, 32B rows
    unsigned* t1B = (unsigned*)(base + off); off += (size_t)NN * 32;
    __half* t2A = (__half*)(base + off); off += (size_t)NN * 32;      // fp16, 32B rows
    __half* t2B = (__half*)(base + off); off += (size_t)NN * 32;
    float* corr = (float*)(base + off); off += (size_t)NB * 256 * 4;  // 8KB accum

    dim3 blk(256);
    k_pack<<<dim3(1024), blk, 0, stream>>>(xA, xB, x4A, x4B, corr);
    k_gcn1<<<dim3(1024), blk, 0, stream>>>(srcA, srcB, x4A, x4B, W1, b1, W2, t1A, t1B);
    k_gcn2<<<dim3(1024), blk, 0, stream>>>(srcA, srcB, t1A, t1B, b2, W3, t2A, t2B);
    k_gcn3corr<<<dim3(1024), blk, 0, stream>>>(srcA, srcB, t2A, t2B, b3, corr);
    k_head<<<dim3(1), dim3(512), 0, stream>>>(corr, c1w, c1b, g1, be1,
                                              c2w, c2b, g2, be2, lw, lb,
                                              (float*)d_out);
}

// Round 15
// 92.924 us; speedup vs baseline: 1.0767x; 1.0767x over previous
//
#include <hip/hip_runtime.h>
#include <hip/hip_fp16.h>

// ProsGraphNet on MI355X — R15 = R13 (verified 93.0us best; R14's 32-deep
// window regressed -7%: occupancy loss at TA request-rate cap).
// Final model: 21M divergent 16B lane-requests @ ~0.6 req/cyc/CU ≈ 57us
// gather wall + ~30us fixed (pack/heads/launch gaps/atomics).
//  - every node has exactly DEG=16 in-edges -> deg == 17, coef == 1/17
//  - edges sorted by dst: node i's incoming srcs are src[16i..16i+15]
//  - graph g -> XCD g (blockIdx&7): gathers hit the 4MB per-XCD L2
//  - t1 fp8 e4m3 32B rows, t2 fp16 32B rows (hybrid; t2-fp8 fails accuracy)
//  - sched_barrier(0)-forced 16-deep gather windows (R12: -11us)
//  - fp32 atomic corr accumulation, zeroed in k_pack (R13: -3us)

#define NN 131072
#define SS 16384
#define NB 8
#define DEG 16
#define INV17 (1.0f / 17.0f)

typedef float floatx2 __attribute__((ext_vector_type(2)));

__device__ __forceinline__ unsigned pkh2(float a, float b) {
    union { __half2 h2; unsigned u; } c;
    c.h2 = __floats2half2_rn(a, b);
    return c.u;
}

__device__ __forceinline__ unsigned pk4fp8(float a, float b, float c, float d) {
    unsigned lo = __builtin_amdgcn_cvt_pk_fp8_f32(a, b, 0, false);
    return __builtin_amdgcn_cvt_pk_fp8_f32(c, d, lo, true);
}

// accumulate 4 fp8 values packed in uint32 u into acc[base..base+4)
#define ACCU32(acc, base, u) { \
    floatx2 lo_ = __builtin_amdgcn_cvt_pk_f32_fp8((u), false); \
    floatx2 hi_ = __builtin_amdgcn_cvt_pk_f32_fp8((u), true); \
    acc[(base) + 0] += lo_[0]; acc[(base) + 1] += lo_[1]; \
    acc[(base) + 2] += hi_[0]; acc[(base) + 3] += hi_[1]; }

// accumulate a 32B fp16 row (2 uint4 = 8 half2) into a[8]
#define HACC8(a, r0, r1) { \
    const __half2* p_ = reinterpret_cast<const __half2*>(&(r0)); \
    a[0] = __hadd2(a[0], p_[0]); a[1] = __hadd2(a[1], p_[1]); \
    a[2] = __hadd2(a[2], p_[2]); a[3] = __hadd2(a[3], p_[3]); \
    p_ = reinterpret_cast<const __half2*>(&(r1)); \
    a[4] = __hadd2(a[4], p_[0]); a[5] = __hadd2(a[5], p_[1]); \
    a[6] = __hadd2(a[6], p_[2]); a[7] = __hadd2(a[7], p_[3]); }

// ---- pack x (N,3) fp32 -> float4 rows, XCD-affine; blocks 0..7 zero corr -
__global__ __launch_bounds__(256) void k_pack(
    const float* __restrict__ xA, const float* __restrict__ xB,
    float4* __restrict__ x4A, float4* __restrict__ x4B,
    float* __restrict__ corr) {
    int b = blockIdx.x;
    if (b < 8) corr[b * 256 + threadIdx.x] = 0.0f;    // zero accumulators
    int g = b & 7, side = (b >> 3) & 1, chunk = b >> 4;   // 1024 blocks
    const float* x = side ? xB : xA;
    float4* x4 = side ? x4B : x4A;
    int i = g * SS + chunk * 256 + threadIdx.x;
    x4[i] = make_float4(x[3 * i], x[3 * i + 1], x[3 * i + 2], 0.0f);
}

// ---- layer1: agg(x4) -> @W1+b1 -> relu -> @W2 -> t1 fp8 32B rows --------
__global__ __launch_bounds__(256, 4) void k_gcn1(
    const int* __restrict__ srcA, const int* __restrict__ srcB,
    const float4* __restrict__ x4A, const float4* __restrict__ x4B,
    const float* __restrict__ W1, const float* __restrict__ b1,
    const float* __restrict__ W2,
    unsigned* __restrict__ t1A, unsigned* __restrict__ t1B) {
    int b = blockIdx.x;
    int g = b & 7, side = (b >> 3) & 1, chunk = b >> 4;   // 1024 blocks
    const int* src = side ? srcB : srcA;
    const float4* x4 = side ? x4B : x4A;
    unsigned* t1 = side ? t1B : t1A;
    int i = g * SS + chunk * 256 + threadIdx.x;

    const int4* sp = reinterpret_cast<const int4*>(src + (size_t)i * DEG);
    int4 s0 = sp[0], s1 = sp[1], s2 = sp[2], s3 = sp[3];
    int nb[16] = {s0.x, s0.y, s0.z, s0.w, s1.x, s1.y, s1.z, s1.w,
                  s2.x, s2.y, s2.z, s2.w, s3.x, s3.y, s3.z, s3.w};

    float4 self = x4[i];
    float4 v[16];
#pragma unroll
    for (int k = 0; k < 16; ++k) v[k] = x4[nb[k]];
    __builtin_amdgcn_sched_barrier(0);     // all 16 gathers issued first
    float ax0 = self.x, ay0 = self.y, az0 = self.z;
    float ax1 = 0.f, ay1 = 0.f, az1 = 0.f;
#pragma unroll
    for (int k = 0; k < 16; k += 2) {
        ax0 += v[k].x; ay0 += v[k].y; az0 += v[k].z;
        ax1 += v[k + 1].x; ay1 += v[k + 1].y; az1 += v[k + 1].z;
    }
    float ax = (ax0 + ax1) * INV17, ay = (ay0 + ay1) * INV17, az = (az0 + az1) * INV17;

    float h[32];
#pragma unroll
    for (int k = 0; k < 32; ++k) {
        float hv = fmaf(ax, W1[k], fmaf(ay, W1[32 + k], fmaf(az, W1[64 + k], b1[k])));
        h[k] = fmaxf(hv, 0.0f);
    }
    float t[24];
#pragma unroll
    for (int j = 0; j < 24; ++j) t[j] = 0.0f;
#pragma unroll
    for (int k = 0; k < 32; ++k) {
        float hv = h[k];
#pragma unroll
        for (int j = 0; j < 24; ++j) t[j] = fmaf(hv, W2[k * 24 + j], t[j]);
    }
    uint4* row = reinterpret_cast<uint4*>(t1 + (size_t)i * 8);   // 32B rows
    row[0] = make_uint4(pk4fp8(t[0], t[1], t[2], t[3]),
                        pk4fp8(t[4], t[5], t[6], t[7]),
                        pk4fp8(t[8], t[9], t[10], t[11]),
                        pk4fp8(t[12], t[13], t[14], t[15]));
    row[1] = make_uint4(pk4fp8(t[16], t[17], t[18], t[19]),
                        pk4fp8(t[20], t[21], t[22], t[23]), 0u, 0u);
}

// ---- layer2: agg(t1 fp8)+b2 -> relu -> @W3 -> t2 fp16 32B rows ----------
// 2 batches x 8 rows; sched_barrier forces 16 loads/batch in flight.
__global__ __launch_bounds__(256, 4) void k_gcn2(
    const int* __restrict__ srcA, const int* __restrict__ srcB,
    const unsigned* __restrict__ t1A, const unsigned* __restrict__ t1B,
    const float* __restrict__ b2, const float* __restrict__ W3,
    __half* __restrict__ t2A, __half* __restrict__ t2B) {
    int b = blockIdx.x;
    int g = b & 7, side = (b >> 3) & 1, chunk = b >> 4;   // 1024 blocks
    const int* src = side ? srcB : srcA;
    const uint4* t1v = reinterpret_cast<const uint4*>(side ? t1B : t1A); // row = 2 uint4
    __half* t2 = side ? t2B : t2A;
    int i = g * SS + chunk * 256 + threadIdx.x;

    const int4* sp = reinterpret_cast<const int4*>(src + (size_t)i * DEG);
    int4 s0 = sp[0], s1 = sp[1], s2 = sp[2], s3 = sp[3];
    int nb[16] = {s0.x, s0.y, s0.z, s0.w, s1.x, s1.y, s1.z, s1.w,
                  s2.x, s2.y, s2.z, s2.w, s3.x, s3.y, s3.z, s3.w};

    float acc[24];
#pragma unroll
    for (int j = 0; j < 24; ++j) acc[j] = 0.0f;
    {   // self row (coalesced)
        uint4 r0 = t1v[(size_t)i * 2], r1 = t1v[(size_t)i * 2 + 1];
        ACCU32(acc, 0, r0.x); ACCU32(acc, 4, r0.y);
        ACCU32(acc, 8, r0.z); ACCU32(acc, 12, r0.w);
        ACCU32(acc, 16, r1.x); ACCU32(acc, 20, r1.y);
    }
#pragma unroll
    for (int kb = 0; kb < 2; ++kb) {
        uint4 ra[8], rb[8];
#pragma unroll
        for (int k = 0; k < 8; ++k) {
            int base = nb[8 * kb + k] * 2;
            ra[k] = t1v[base]; rb[k] = t1v[base + 1];
        }
        __builtin_amdgcn_sched_barrier(0);     // 16 loads issued before any cvt
#pragma unroll
        for (int k = 0; k < 8; ++k) {
            ACCU32(acc, 0, ra[k].x); ACCU32(acc, 4, ra[k].y);
            ACCU32(acc, 8, ra[k].z); ACCU32(acc, 12, ra[k].w);
            ACCU32(acc, 16, rb[k].x); ACCU32(acc, 20, rb[k].y);
        }
    }
    float z[24];
#pragma unroll
    for (int j = 0; j < 24; ++j)
        z[j] = fmaxf(fmaf(acc[j], INV17, b2[j]), 0.0f);

    float o[16];
#pragma unroll
    for (int j = 0; j < 16; ++j) o[j] = 0.0f;
#pragma unroll
    for (int k = 0; k < 24; ++k) {
        const float4* wr = reinterpret_cast<const float4*>(W3 + k * 16);
        float4 w0 = wr[0], w1 = wr[1], w2 = wr[2], w3 = wr[3];
        float zk = z[k];
        o[0] = fmaf(zk, w0.x, o[0]);  o[1] = fmaf(zk, w0.y, o[1]);
        o[2] = fmaf(zk, w0.z, o[2]);  o[3] = fmaf(zk, w0.w, o[3]);
        o[4] = fmaf(zk, w1.x, o[4]);  o[5] = fmaf(zk, w1.y, o[5]);
        o[6] = fmaf(zk, w1.z, o[6]);  o[7] = fmaf(zk, w1.w, o[7]);
        o[8] = fmaf(zk, w2.x, o[8]);  o[9] = fmaf(zk, w2.y, o[9]);
        o[10] = fmaf(zk, w2.z, o[10]); o[11] = fmaf(zk, w2.w, o[11]);
        o[12] = fmaf(zk, w3.x, o[12]); o[13] = fmaf(zk, w3.y, o[13]);
        o[14] = fmaf(zk, w3.z, o[14]); o[15] = fmaf(zk, w3.w, o[15]);
    }
    uint4* out = reinterpret_cast<uint4*>((char*)t2 + (size_t)i * 32);
    out[0] = make_uint4(pkh2(o[0], o[1]), pkh2(o[2], o[3]), pkh2(o[4], o[5]), pkh2(o[6], o[7]));
    out[1] = make_uint4(pkh2(o[8], o[9]), pkh2(o[10], o[11]), pkh2(o[12], o[13]), pkh2(o[14], o[15]));
}

// ---- layer3 + corr: agg(t2 fp16)+b3 -> l2norm -> LDS -> atomic corr -----
// 256 threads = 128 nodes x 2 sides; sched_barrier-forced 16-load batches.
__global__ __launch_bounds__(256, 4) void k_gcn3corr(
    const int* __restrict__ srcA, const int* __restrict__ srcB,
    const __half* __restrict__ t2A, const __half* __restrict__ t2B,
    const float* __restrict__ b3, float* __restrict__ corr) {
    __shared__ float sF[2 * 128 * 20];    // stride 20 floats: bank-safe
    int b = blockIdx.x;
    int g = b & 7, chunk = b >> 3;        // chunk 0..127
    int t = threadIdx.x;
    int s = t >> 7, n = t & 127;
    const int* src = s ? srcB : srcA;
    const uint4* t2v = reinterpret_cast<const uint4*>(s ? t2B : t2A);  // row = 2 uint4
    int i = g * SS + chunk * 128 + n;

    const int4* sp = reinterpret_cast<const int4*>(src + (size_t)i * DEG);
    int4 s0 = sp[0], s1 = sp[1], s2 = sp[2], s3 = sp[3];
    int nb[16] = {s0.x, s0.y, s0.z, s0.w, s1.x, s1.y, s1.z, s1.w,
                  s2.x, s2.y, s2.z, s2.w, s3.x, s3.y, s3.z, s3.w};

    __half2 accA[8], accB[8];
    {
        uint4 r0 = t2v[(size_t)i * 2], r1 = t2v[(size_t)i * 2 + 1];
        const __half2* p = reinterpret_cast<const __half2*>(&r0);
        accA[0] = p[0]; accA[1] = p[1]; accA[2] = p[2]; accA[3] = p[3];
        p = reinterpret_cast<const __half2*>(&r1);
        accA[4] = p[0]; accA[5] = p[1]; accA[6] = p[2]; accA[7] = p[3];
        __half2 z2v = __floats2half2_rn(0.0f, 0.0f);
#pragma unroll
        for (int j = 0; j < 8; ++j) accB[j] = z2v;
    }
#pragma unroll
    for (int kb = 0; kb < 2; ++kb) {
        uint4 ra[8], rb[8];
#pragma unroll
        for (int k = 0; k < 8; ++k) {
            int base = nb[8 * kb + k] * 2;
            ra[k] = t2v[base]; rb[k] = t2v[base + 1];
        }
        __builtin_amdgcn_sched_barrier(0);     // 16 loads issued before any add
#pragma unroll
        for (int k = 0; k < 8; k += 2) {
            HACC8(accA, ra[k], rb[k]);
            HACC8(accB, ra[k + 1], rb[k + 1]);
        }
    }
    float acc[16];
#pragma unroll
    for (int j = 0; j < 8; ++j) {
        __half2 sum = __hadd2(accA[j], accB[j]);
        acc[2 * j] = __low2float(sum);
        acc[2 * j + 1] = __high2float(sum);
    }
    float ss = 0.0f;
#pragma unroll
    for (int j = 0; j < 16; ++j) {
        acc[j] = fmaf(acc[j], INV17, b3[j]);
        ss = fmaf(acc[j], acc[j], ss);
    }
    float sc = rsqrtf(ss + 1e-6f);
    float* dst = &sF[(s * 128 + n) * 20];
#pragma unroll
    for (int c = 0; c < 4; ++c)
        reinterpret_cast<float4*>(dst)[c] =
            make_float4(acc[4 * c] * sc, acc[4 * c + 1] * sc,
                        acc[4 * c + 2] * sc, acc[4 * c + 3] * sc);
    __syncthreads();

    int c = t >> 4, d = t & 15;
    const float* sA = sF;
    const float* sB = sF + 128 * 20;
    float pacc = 0.0f;
#pragma unroll 8
    for (int m = 0; m < 128; ++m)
        pacc = fmaf(sA[m * 20 + c], sB[m * 20 + d], pacc);
    atomicAdd(&corr[g * 256 + t], pacc);   // XCD-local L2 atomic, 128/addr
}

// ---- head stage 1: corr -> relu -> l2norm(c) -> conv1 4x4 -> y1 ---------
__global__ __launch_bounds__(256) void k_head1(const float* __restrict__ corr,
                                               const float* __restrict__ c1w,
                                               const float* __restrict__ c1b,
                                               float* __restrict__ y1) {
    __shared__ float cn[256];
    __shared__ float scale[16];
    __shared__ float ph[256];
    int t = threadIdx.x, g = blockIdx.x;
    cn[t] = fmaxf(corr[g * 256 + t], 0.0f);
    __syncthreads();
    if (t < 16) {
        float q = 0.0f;
        for (int c = 0; c < 16; ++c) { float v = cn[c * 16 + t]; q = fmaf(v, v, q); }
        scale[t] = rsqrtf(q + 1e-6f);
    }
    __syncthreads();
    float v = cn[t] * scale[t & 15];
    __syncthreads();
    cn[t] = v;
    __syncthreads();
    int o = t >> 1, half = t & 1;
    const float4* w = reinterpret_cast<const float4*>(c1w + o * 256 + half * 128);
    const float4* cc = reinterpret_cast<const float4*>(cn + half * 128);
    float a = 0.0f;
#pragma unroll
    for (int q = 0; q < 32; ++q) {
        float4 wv = w[q]; float4 cv = cc[q];
        a = fmaf(wv.x, cv.x, a); a = fmaf(wv.y, cv.y, a);
        a = fmaf(wv.z, cv.z, a); a = fmaf(wv.w, cv.w, a);
    }
    ph[t] = a;
    __syncthreads();
    if (t < 128) y1[g * 128 + t] = ph[2 * t] + ph[2 * t + 1] + c1b[t];
}

// ---- head stage 2: BN1+relu, conv2(center tap)+BN2+relu, linear ----------
__global__ __launch_bounds__(512) void k_head2(const float* __restrict__ y1,
                                               const float* __restrict__ g1,
                                               const float* __restrict__ be1,
                                               const float* __restrict__ c2w,
                                               const float* __restrict__ c2b,
                                               const float* __restrict__ g2,
                                               const float* __restrict__ be2,
                                               const float* __restrict__ lw,
                                               const float* __restrict__ lb,
                                               float* __restrict__ out) {
    __shared__ float z1[1024];
    __shared__ float w2t[8192];
    __shared__ float y2[512];
    __shared__ float z2[512];
    int t = threadIdx.x;
    if (t < 128) {
        float m = 0.0f;
        for (int b = 0; b < 8; ++b) m += y1[b * 128 + t];
        m *= 0.125f;
        float v = 0.0f;
        for (int b = 0; b < 8; ++b) { float d = y1[b * 128 + t] - m; v = fmaf(d, d, v); }
        v *= 0.125f;
        float sc = rsqrtf(v + 1e-5f) * g1[t], sh = be1[t];
        for (int b = 0; b < 8; ++b)
            z1[b * 128 + t] = fmaxf(fmaf(y1[b * 128 + t] - m, sc, sh), 0.0f);
    }
    int o2 = t & 63, cb = (t >> 6) * 16;
    for (int k = 0; k < 16; ++k) {
        int c = cb + k;
        w2t[c * 64 + o2] = c2w[(o2 * 128 + c) * 9 + 4];
    }
    __syncthreads();
    {
        int b = t >> 6;
        float a = 0.0f;
        for (int c = 0; c < 128; ++c) a = fmaf(z1[b * 128 + c], w2t[c * 64 + o2], a);
        y2[t] = a + c2b[o2];
    }
    __syncthreads();
    if (t < 64) {
        float m = 0.0f;
        for (int b = 0; b < 8; ++b) m += y2[b * 64 + t];
        m *= 0.125f;
        float v = 0.0f;
        for (int b = 0; b < 8; ++b) { float d = y2[b * 64 + t] - m; v = fmaf(d, d, v); }
        v *= 0.125f;
        float sc = rsqrtf(v + 1e-5f) * g2[t], sh = be2[t];
        for (int b = 0; b < 8; ++b)
            z2[b * 64 + t] = fmaxf(fmaf(y2[b * 64 + t] - m, sc, sh), 0.0f);
    }
    __syncthreads();
    if (t < 48) {
        int b = t / 6, k = t - b * 6;
        float a = 0.0f;
        for (int c = 0; c < 64; ++c) a = fmaf(z2[b * 64 + c], lw[k * 64 + c], a);
        float th = 0.1f * (a + lb[k]);
        const float ident[6] = {1.0f, 0.0f, 0.0f, 0.0f, 1.0f, 0.0f};
        out[t] = th + ident[k];
    }
}

extern "C" void kernel_launch(void* const* d_in, const int* in_sizes, int n_in,
                              void* d_out, int out_size, void* d_ws, size_t ws_size,
                              hipStream_t stream) {
    const float* xA = (const float*)d_in[0];
    const float* xB = (const float*)d_in[1];
    const int* srcA = (const int*)d_in[2];
    const int* srcB = (const int*)d_in[3];
    const float* W1 = (const float*)d_in[4];
    const float* b1 = (const float*)d_in[5];
    const float* W2 = (const float*)d_in[6];
    const float* b2 = (const float*)d_in[7];
    const float* W3 = (const float*)d_in[8];
    const float* b3 = (const float*)d_in[9];
    const float* c1w = (const float*)d_in[10];
    const float* c1b = (const float*)d_in[11];
    const float* g1 = (const float*)d_in[12];
    const float* be1 = (const float*)d_in[13];
    const float* c2w = (const float*)d_in[14];
    const float* c2b = (const float*)d_in[15];
    const float* g2 = (const float*)d_in[16];
    const float* be2 = (const float*)d_in[17];
    const float* lw = (const float*)d_in[18];
    const float* lb = (const float*)d_in[19];

    char* base = (char*)d_ws;
    size_t off = 0;
    float4* x4A = (float4*)(base + off); off += (size_t)NN * 16;
    float4* x4B = (float4*)(base + off); off += (size_t)NN * 16;
    unsigned* t1A = (unsigned*)(base + off); off += (size_t)NN * 32;  // fp8, 32B rows
    unsigned* t1B = (unsigned*)(base + off); off += (size_t)NN * 32;
    __half* t2A = (__half*)(base + off); off += (size_t)NN * 32;      // fp16, 32B rows
    __half* t2B = (__half*)(base + off); off += (size_t)NN * 32;
    float* corr = (float*)(base + off); off += (size_t)NB * 256 * 4;  // 8KB accum
    float* y1 = (float*)(base + off);

    dim3 blk(256);
    k_pack<<<dim3(1024), blk, 0, stream>>>(xA, xB, x4A, x4B, corr);
    k_gcn1<<<dim3(1024), blk, 0, stream>>>(srcA, srcB, x4A, x4B, W1, b1, W2, t1A, t1B);
    k_gcn2<<<dim3(1024), blk, 0, stream>>>(srcA, srcB, t1A, t1B, b2, W3, t2A, t2B);
    k_gcn3corr<<<dim3(1024), blk, 0, stream>>>(srcA, srcB, t2A, t2B, b3, corr);
    k_head1<<<dim3(NB), blk, 0, stream>>>(corr, c1w, c1b, y1);
    k_head2<<<dim3(1), dim3(512), 0, stream>>>(y1, g1, be1, c2w, c2b, g2, be2, lw, lb,
                                               (float*)d_out);
}